// Round 13
// baseline (2049.855 us; speedup 1.0000x reference)
//
#include <hip/hip_runtime.h>
#include <cstdint>

// Problem constants
#define NROWS   131072
#define NUNITS  256
#define KTOT    512          // INPUT_DIM + UNITS
#define BM      256          // rows per block
#define THREADS 512

typedef float f32x4  __attribute__((ext_vector_type(4)));
typedef short bf16x8 __attribute__((ext_vector_type(8)));

__device__ __forceinline__ short f2bf(float x) {
    unsigned u = __float_as_uint(x);
    u += 0x7FFFu + ((u >> 16) & 1u);   // round-to-nearest-even
    return (short)(u >> 16);
}

// W [512][1024] fp32 -> Wws [16][1024][32] bf16 (B-fragment order, L2-resident).
__global__ void convert_W_kernel(const float* __restrict__ W, short* __restrict__ Wws) {
    int i = blockIdx.x * 256 + threadIdx.x;       // 0 .. 524287
    int k = i >> 10;
    int c = i & 1023;
    Wws[((size_t)(k >> 5) << 15) + ((size_t)c << 5) + (k & 31)] = f2bf(W[i]);
}

// Main: grid 2048 = 512 row-tiles x 4 u-tiles (XCD-swizzled: 4 u-tiles of a row
// panel co-locate on one XCD -> fp32 A panel HBM-fetched once, L2-served 3x).
// Block: 256 rows x 64 u x 4 gates. 8 waves = 2 row-halves(128r) x 4 quarters;
// wave tile 128x64, acc[8][4] (all 4 gates lane-local -> fused epilogue).
// Phase p (fully unrolled, 16 phases of BK=32), R12 pipeline at 2x volume:
//   dmaB(p+1) [2 gload_lds] -> glbA(p+2) [4 dwordx4 fp32] ->
//   writeA(p+1) [auto vmcnt(6); 8 cvt_pk + 2 ds_write_b128, BEFORE compute] ->
//   compute(p) [12 ds_read_b128 + 32 MFMA, setprio] ->
//   s_waitcnt vmcnt(4) lgkmcnt(0)  [retire B(p+1); glbA(p+2) stays in flight]
//   s_barrier
// 32 MFMA/barrier/wave (2x R12) with LDS still 64KB -> 2 blocks/CU preserved.
// Layouts: R7/R10/R12-verified conflict-free (64B row stride, granule XOR
// (row>>1)&3; B swizzle on gload_lds SOURCE (rule #21), A on per-lane ds_write).
__global__ void __launch_bounds__(THREADS, 4)
lstm_main_kernel(const float* __restrict__ x, const float* __restrict__ h_prev,
                 const float* __restrict__ c_prev, const float* __restrict__ bias,
                 const float* __restrict__ pi, const float* __restrict__ pf,
                 const float* __restrict__ po, const short* __restrict__ Wws,
                 float* __restrict__ out) {
    __shared__ short Ab[2][8192];   // 2 x 16 KB bf16 A tiles [256r][32k] swizzled
    __shared__ short Bb[2][8192];   // 2 x 16 KB bf16 B tiles

    const int bid = blockIdx.x;
    const int swz = (bid & 7) * 256 + (bid >> 3);
    const int ut  = swz & 3;
    const int rt  = swz >> 2;
    const int row0 = rt * BM;

    const int t    = threadIdx.x;
    const int lane = t & 63;
    const int w    = t >> 6;
    const int lr   = lane & 15;
    const int hi   = lane >> 4;          // k-granule 0..3
    const int rh   = w >> 2;             // row half 0..1 (128 rows each)
    const int q    = w & 3;              // col quarter 0..3

    // ---- A staging: thread t -> rows t>>2 and t>>2+128, source granule t&3 ----
    const int arow = t >> 2, ag = t & 3;
    const int avoff = ((row0 + arow) * 256 + ag * 8) * 4;          // bytes (rep0)
    const int awr   = arow * 32 + ((ag ^ ((arow >> 1) & 3)) * 8);  // LDS shorts
    // rep1: +128 rows => avoff + 131072 bytes; XOR unchanged ((r+128)>>1 mod 4 == r>>1 mod 4)
    // => awr + 4096 shorts.

    // ---- B DMA source byte-offsets (R12 scheme, 0 conflicts measured) ----
    const int u0  = (t >> 2) & 63;
    const int bg0 = t >> 8;              // 0..1
    const int bsw = ((t & 3) ^ ((t >> 3) & 3)) * 8;
    const int bvoff0 = (((bg0    ) * 256 + ut * 64 + u0) * 32 + bsw) * 2;
    const int bvoff1 = (((bg0 + 2) * 256 + ut * 64 + u0) * 32 + bsw) * 2;

    // ---- fragment read offsets (shorts): swizzle matches write side ----
    const int sw   = (hi ^ ((lr >> 1) & 3)) * 8;
    const int aoff = (rh * 128 + lr) * 32 + sw;          // + m*512, m=0..7
    const int boff = (q * 16 + lr) * 32 + sw;            // + g*2048

    f32x4 acc[8][4];
    #pragma unroll
    for (int m = 0; m < 8; ++m)
        #pragma unroll
        for (int g = 0; g < 4; ++g)
            acc[m][g] = (f32x4){0.f, 0.f, 0.f, 0.f};

    f32x4 sreg[2][4];                    // two in-flight A register sets (parity)
    auto glbA = [&](int p) {
        const char* base = (const char*)(p < 8 ? x : h_prev) + ((p & 7) << 7);
        sreg[p & 1][0] = *(const f32x4*)(base + avoff);
        sreg[p & 1][1] = *(const f32x4*)(base + avoff + 16);
        sreg[p & 1][2] = *(const f32x4*)(base + avoff + 131072);
        sreg[p & 1][3] = *(const f32x4*)(base + avoff + 131072 + 16);
    };
    auto writeA = [&](int p) {
        const f32x4* s = sreg[p & 1];
        unsigned v0, v1, v2, v3, v4, v5, v6, v7;
        asm("v_cvt_pk_bf16_f32 %0, %1, %2" : "=v"(v0) : "v"(s[0][0]), "v"(s[0][1]));
        asm("v_cvt_pk_bf16_f32 %0, %1, %2" : "=v"(v1) : "v"(s[0][2]), "v"(s[0][3]));
        asm("v_cvt_pk_bf16_f32 %0, %1, %2" : "=v"(v2) : "v"(s[1][0]), "v"(s[1][1]));
        asm("v_cvt_pk_bf16_f32 %0, %1, %2" : "=v"(v3) : "v"(s[1][2]), "v"(s[1][3]));
        asm("v_cvt_pk_bf16_f32 %0, %1, %2" : "=v"(v4) : "v"(s[2][0]), "v"(s[2][1]));
        asm("v_cvt_pk_bf16_f32 %0, %1, %2" : "=v"(v5) : "v"(s[2][2]), "v"(s[2][3]));
        asm("v_cvt_pk_bf16_f32 %0, %1, %2" : "=v"(v6) : "v"(s[3][0]), "v"(s[3][1]));
        asm("v_cvt_pk_bf16_f32 %0, %1, %2" : "=v"(v7) : "v"(s[3][2]), "v"(s[3][3]));
        *(int4*)&Ab[p & 1][awr]        = make_int4((int)v0, (int)v1, (int)v2, (int)v3);
        *(int4*)&Ab[p & 1][awr + 4096] = make_int4((int)v4, (int)v5, (int)v6, (int)v7);
    };
    auto dmaB = [&](int p) {
        const char* wb = (const char*)Wws + ((size_t)p << 16);
        short* dst = &Bb[p & 1][0];
        __builtin_amdgcn_global_load_lds(
            (const __attribute__((address_space(1))) uint32_t*)(const void*)(wb + bvoff0),
            (__attribute__((address_space(3))) uint32_t*)(void*)(dst + t * 8), 16, 0, 0);
        __builtin_amdgcn_global_load_lds(
            (const __attribute__((address_space(1))) uint32_t*)(const void*)(wb + bvoff1),
            (__attribute__((address_space(3))) uint32_t*)(void*)(dst + 4096 + t * 8), 16, 0, 0);
    };
    auto compute = [&](int p) {
        const short* A = &Ab[p & 1][0];
        const short* B = &Bb[p & 1][0];
        bf16x8 af[8], bfr[4];
        #pragma unroll
        for (int m = 0; m < 8; ++m)
            af[m] = *(const bf16x8*)&A[aoff + m * 512];
        #pragma unroll
        for (int g = 0; g < 4; ++g)
            bfr[g] = *(const bf16x8*)&B[boff + g * 2048];
        __builtin_amdgcn_s_setprio(1);
        #pragma unroll
        for (int g = 0; g < 4; ++g)
            #pragma unroll
            for (int m = 0; m < 8; ++m)
                acc[m][g] = __builtin_amdgcn_mfma_f32_16x16x32_bf16(af[m], bfr[g], acc[m][g], 0, 0, 0);
        __builtin_amdgcn_s_setprio(0);
    };

    // ---- prologue: A(0) published; B(0) retired; glbA(1) left in flight ----
    glbA(0);
    dmaB(0);
    glbA(1);
    writeA(0);                            // auto-wait retires glbA(0)
    asm volatile("s_waitcnt vmcnt(4) lgkmcnt(0)" ::: "memory");  // B(0) done; glbA(1) in flight
    __builtin_amdgcn_s_barrier();

    #pragma unroll
    for (int p = 0; p < 16; ++p) {
        if (p <= 14) dmaB(p + 1);         // B lookahead 1 (L2-resident)
        if (p <= 13) glbA(p + 2);         // A lookahead 2 (HBM latency covered)
        if (p <= 14) writeA(p + 1);       // auto vmcnt(6): B(p+1)+glbA(p+2) in flight
        compute(p);
        if (p <= 13) {
            asm volatile("s_waitcnt vmcnt(4) lgkmcnt(0)" ::: "memory");  // retire B(p+1)
            __builtin_amdgcn_s_barrier();
        } else if (p == 14) {
            asm volatile("s_waitcnt vmcnt(0) lgkmcnt(0)" ::: "memory");
            __builtin_amdgcn_s_barrier();
        }
    }

    // ---- fused LSTM epilogue (lane-local: all 4 gates in acc[m][0..3]) ----
    const size_t HS = (size_t)NROWS * NUNITS;
    const int u = ut * 64 + q * 16 + lr;
    const float bi = bias[u],       bfg = bias[256 + u];
    const float bc = bias[512 + u], bo  = bias[768 + u];
    const float ppi = pi[u], ppf = pf[u], ppo = po[u];
    #pragma unroll
    for (int m = 0; m < 8; ++m) {
        #pragma unroll
        for (int r = 0; r < 4; ++r) {
            const int row = row0 + rh * 128 + m * 16 + hi * 4 + r;
            const size_t o = (size_t)row * NUNITS + u;
            const float cp = c_prev[o];
            float zi = acc[m][0][r] + bi  + ppi * cp;
            float zf = acc[m][1][r] + bfg + ppf * cp;
            float zc = acc[m][2][r] + bc;
            float zo = acc[m][3][r] + bo  + ppo * cp;
            float ig = 1.f / (1.f + __expf(-zi));
            float fg = 1.f / (1.f + __expf(-zf));
            float og = 1.f / (1.f + __expf(-zo));
            zc = fminf(fmaxf(zc, -30.f), 30.f);
            float e2 = __expf(2.f * zc);
            float chat = (e2 - 1.f) / (e2 + 1.f);
            float c  = fg * cp + ig * chat;
            float ccl = fminf(fmaxf(c, -30.f), 30.f);
            float e3 = __expf(2.f * ccl);
            float th = (e3 - 1.f) / (e3 + 1.f);
            float h  = og * th;
            out[o]          = h;
            out[HS + o]     = h;
            out[2 * HS + o] = c;
        }
    }
}

extern "C" void kernel_launch(void* const* d_in, const int* in_sizes, int n_in,
                              void* d_out, int out_size, void* d_ws, size_t ws_size,
                              hipStream_t stream) {
    const float* x  = (const float*)d_in[0];
    const float* h  = (const float*)d_in[1];
    const float* c  = (const float*)d_in[2];
    const float* W  = (const float*)d_in[3];
    const float* b  = (const float*)d_in[4];
    const float* pi = (const float*)d_in[5];
    const float* pf = (const float*)d_in[6];
    const float* po = (const float*)d_in[7];
    float* out = (float*)d_out;

    short* Wws = (short*)d_ws;            // 1 MiB bf16 copy of W in B-frag order

    hipLaunchKernelGGL(convert_W_kernel, dim3(2048), dim3(256), 0, stream, W, Wws);
    hipLaunchKernelGGL(lstm_main_kernel, dim3(NROWS / BM * 4), dim3(THREADS), 0, stream,
                       x, h, c, b, pi, pf, po, Wws, out);
}

// Round 14
// 332.161 us; speedup vs baseline: 6.1713x; 6.1713x over previous
//
#include <hip/hip_runtime.h>
#include <cstdint>

// Problem constants
#define NROWS   131072
#define NUNITS  256
#define KTOT    512          // INPUT_DIM + UNITS
#define BM      128          // rows per block
#define THREADS 512

typedef float f32x4  __attribute__((ext_vector_type(4)));
typedef short bf16x8 __attribute__((ext_vector_type(8)));

__device__ __forceinline__ short f2bf(float x) {
    unsigned u = __float_as_uint(x);
    u += 0x7FFFu + ((u >> 16) & 1u);   // round-to-nearest-even
    return (short)(u >> 16);
}

// W [512][1024] fp32 -> Wws [16][1024][32] bf16 (B-fragment order, L2-resident).
// A wave's B-frag load (16 cols x 16B granule) = one coalesced 1 KiB region.
__global__ void convert_W_kernel(const float* __restrict__ W, short* __restrict__ Wws) {
    int i = blockIdx.x * 256 + threadIdx.x;       // 0 .. 524287
    int k = i >> 10;
    int c = i & 1023;
    Wws[((size_t)(k >> 5) << 15) + ((size_t)c << 5) + (k & 31)] = f2bf(W[i]);
}

// Main: grid 4096 = 1024 row-tiles x 4 u-tiles (XCD-swizzled: the 4 u-tiles of
// a row panel co-locate on one XCD -> fp32 A panel HBM-fetched once, L2-served).
// Block: 128 rows x 64 u x 4 gates. 8 waves = 2 row-halves x 4 col-quarters;
// wave tile 64x64, acc[4][4] (all 4 gates lane-local -> fused epilogue).
// B IS NOT STAGED IN LDS: each wave loads its 4 gate-fragments straight from
// the L2-resident Wws as coalesced dwordx4 register loads (R2-validated
// layout). Only A flows through LDS -> the barrier guards just one
// ds_write_b128/thread; no manual vmcnt anywhere (compiler per-value waits);
// glbA keeps 2-phase lookahead (HBM ~900cyc covered). LDS = 16 KB total.
// A layout: R7/R12-verified conflict-free (64B row stride, granule XOR
// (row>>1)&3 applied on the per-lane ds_write and matched on ds_read).
__global__ void __launch_bounds__(THREADS, 4)
lstm_main_kernel(const float* __restrict__ x, const float* __restrict__ h_prev,
                 const float* __restrict__ c_prev, const float* __restrict__ bias,
                 const float* __restrict__ pi, const float* __restrict__ pf,
                 const float* __restrict__ po, const short* __restrict__ Wws,
                 float* __restrict__ out) {
    __shared__ short Ab[2][4096];   // 2 x 8 KB bf16 A tiles [128r][32k] swizzled

    const int bid = blockIdx.x;
    const int swz = (bid & 7) * 512 + (bid >> 3);
    const int ut  = swz & 3;
    const int rt  = swz >> 2;
    const int row0 = rt * BM;

    const int t    = threadIdx.x;
    const int lane = t & 63;
    const int w    = t >> 6;
    const int lr   = lane & 15;
    const int hi   = lane >> 4;          // k-granule 0..3
    const int rh   = w >> 2;             // row half 0..1
    const int q    = w & 3;              // col quarter 0..3

    // ---- A staging: thread t -> row t>>2, source granule g = t&3 (8 fp32) ----
    const int arow = t >> 2, ag = t & 3;
    const int avoff = ((row0 + arow) * 256 + ag * 8) * 4;          // bytes into x/h
    const int awr   = arow * 32 + ((ag ^ ((arow >> 1) & 3)) * 8);  // LDS shorts

    // ---- B fragment base: col = g*256 + ut*64 + q*16 + lr, granule hi ----
    const int ucol = ut * 64 + q * 16 + lr;
    const short* wfrag = Wws + ((size_t)ucol << 5) + hi * 8;   // + p*32768 + g*8192

    // ---- A fragment read offset (shorts): swizzle matches write side ----
    const int sw   = (hi ^ ((lr >> 1) & 3)) * 8;
    const int aoff = (rh * 64 + lr) * 32 + sw;           // + m*512

    f32x4 acc[4][4];
    #pragma unroll
    for (int m = 0; m < 4; ++m)
        #pragma unroll
        for (int g = 0; g < 4; ++g)
            acc[m][g] = (f32x4){0.f, 0.f, 0.f, 0.f};

    f32x4 sreg[2][2];                    // two in-flight A register sets (parity)
    auto glbA = [&](int p) {
        const char* base = (const char*)(p < 8 ? x : h_prev) + ((p & 7) << 7);
        sreg[p & 1][0] = *(const f32x4*)(base + avoff);
        sreg[p & 1][1] = *(const f32x4*)(base + avoff + 16);
    };
    auto writeA = [&](int p) {
        const f32x4* s = sreg[p & 1];
        unsigned u0_, u1_, u2_, u3_;
        asm("v_cvt_pk_bf16_f32 %0, %1, %2" : "=v"(u0_) : "v"(s[0][0]), "v"(s[0][1]));
        asm("v_cvt_pk_bf16_f32 %0, %1, %2" : "=v"(u1_) : "v"(s[0][2]), "v"(s[0][3]));
        asm("v_cvt_pk_bf16_f32 %0, %1, %2" : "=v"(u2_) : "v"(s[1][0]), "v"(s[1][1]));
        asm("v_cvt_pk_bf16_f32 %0, %1, %2" : "=v"(u3_) : "v"(s[1][2]), "v"(s[1][3]));
        int4 v = make_int4((int)u0_, (int)u1_, (int)u2_, (int)u3_);
        *(int4*)&Ab[p & 1][awr] = v;
    };
    auto compute = [&](int p) {
        const short* A = &Ab[p & 1][0];
        const short* wp = wfrag + ((size_t)p << 15);
        bf16x8 af[4], bfr[4];
        #pragma unroll
        for (int m = 0; m < 4; ++m)
            af[m] = *(const bf16x8*)&A[aoff + m * 512];
        #pragma unroll
        for (int g = 0; g < 4; ++g)
            bfr[g] = *(const bf16x8*)(wp + g * 8192);   // coalesced L2 reg load
        __builtin_amdgcn_s_setprio(1);
        #pragma unroll
        for (int g = 0; g < 4; ++g)
            #pragma unroll
            for (int m = 0; m < 4; ++m)
                acc[m][g] = __builtin_amdgcn_mfma_f32_16x16x32_bf16(af[m], bfr[g], acc[m][g], 0, 0, 0);
        __builtin_amdgcn_s_setprio(0);
    };

    // ---- prologue: A(0) published; glbA(1) in flight ----
    glbA(0);
    glbA(1);
    writeA(0);                            // auto-wait retires glbA(0) only
    asm volatile("s_waitcnt lgkmcnt(0)" ::: "memory");
    __builtin_amdgcn_s_barrier();

    #pragma unroll
    for (int p = 0; p < 16; ++p) {
        if (p <= 13) glbA(p + 2);         // A lookahead 2 (HBM latency covered)
        if (p <= 14) writeA(p + 1);       // auto vmcnt retires glbA(p+1) only
        compute(p);
        if (p <= 14) {
            asm volatile("s_waitcnt lgkmcnt(0)" ::: "memory");   // A writes visible
            __builtin_amdgcn_s_barrier();
        }
    }

    // ---- fused LSTM epilogue (lane-local: all 4 gates in acc[m][0..3]) ----
    const size_t HS = (size_t)NROWS * NUNITS;
    const int u = ucol;
    const float bi = bias[u],       bfg = bias[256 + u];
    const float bc = bias[512 + u], bo  = bias[768 + u];
    const float ppi = pi[u], ppf = pf[u], ppo = po[u];
    #pragma unroll
    for (int m = 0; m < 4; ++m) {
        #pragma unroll
        for (int r = 0; r < 4; ++r) {
            const int row = row0 + rh * 64 + m * 16 + hi * 4 + r;
            const size_t o = (size_t)row * NUNITS + u;
            const float cp = c_prev[o];
            float zi = acc[m][0][r] + bi  + ppi * cp;
            float zf = acc[m][1][r] + bfg + ppf * cp;
            float zc = acc[m][2][r] + bc;
            float zo = acc[m][3][r] + bo  + ppo * cp;
            float ig = 1.f / (1.f + __expf(-zi));
            float fg = 1.f / (1.f + __expf(-zf));
            float og = 1.f / (1.f + __expf(-zo));
            zc = fminf(fmaxf(zc, -30.f), 30.f);
            float e2 = __expf(2.f * zc);
            float chat = (e2 - 1.f) / (e2 + 1.f);
            float c  = fg * cp + ig * chat;
            float ccl = fminf(fmaxf(c, -30.f), 30.f);
            float e3 = __expf(2.f * ccl);
            float th = (e3 - 1.f) / (e3 + 1.f);
            float h  = og * th;
            out[o]          = h;
            out[HS + o]     = h;
            out[2 * HS + o] = c;
        }
    }
}

extern "C" void kernel_launch(void* const* d_in, const int* in_sizes, int n_in,
                              void* d_out, int out_size, void* d_ws, size_t ws_size,
                              hipStream_t stream) {
    const float* x  = (const float*)d_in[0];
    const float* h  = (const float*)d_in[1];
    const float* c  = (const float*)d_in[2];
    const float* W  = (const float*)d_in[3];
    const float* b  = (const float*)d_in[4];
    const float* pi = (const float*)d_in[5];
    const float* pf = (const float*)d_in[6];
    const float* po = (const float*)d_in[7];
    float* out = (float*)d_out;

    short* Wws = (short*)d_ws;            // 1 MiB bf16 copy of W in B-frag order

    hipLaunchKernelGGL(convert_W_kernel, dim3(2048), dim3(256), 0, stream, W, Wws);
    hipLaunchKernelGGL(lstm_main_kernel, dim3(NROWS / BM * 4), dim3(THREADS), 0, stream,
                       x, h, c, b, pi, pf, po, Wws, out);
}

// Round 15
// 314.824 us; speedup vs baseline: 6.5111x; 1.0551x over previous
//
#include <hip/hip_runtime.h>
#include <cstdint>

// Problem constants
#define NROWS   131072
#define NUNITS  256
#define KTOT    512          // INPUT_DIM + UNITS
#define BM      64           // rows per block
#define THREADS 256

typedef float f32x4  __attribute__((ext_vector_type(4)));
typedef short bf16x8 __attribute__((ext_vector_type(8)));

__device__ __forceinline__ short f2bf(float x) {
    unsigned u = __float_as_uint(x);
    u += 0x7FFFu + ((u >> 16) & 1u);   // round-to-nearest-even
    return (short)(u >> 16);
}

// W [512][1024] fp32 -> Wws [16][1024][32] bf16 (B-fragment order, L2-resident).
// A wave's B-frag load (16 cols x 16B granule) = one coalesced 1 KiB region.
__global__ void convert_W_kernel(const float* __restrict__ W, short* __restrict__ Wws) {
    int i = blockIdx.x * 256 + threadIdx.x;       // 0 .. 524287
    int k = i >> 10;
    int c = i & 1023;
    Wws[((size_t)(k >> 5) << 15) + ((size_t)c << 5) + (k & 31)] = f2bf(W[i]);
}

// Main: 256-thread blocks (4 waves) -> 4 blocks/CU = 4 INDEPENDENT barrier
// domains (vs 2 in R12/R14) with 4-wave barriers; this is the lever against
// the measured 82%-latency-bubble regime.
// Grid 8192 = 2048 row-tiles x 4 u-tiles, XCD-swizzled (4 u-tiles of a row
// panel adjacent on one XCD -> fp32 A panel HBM-fetched once, L2-served).
// Block: 64 rows x 64 u x 4 gates; wave w owns cols ut*64 + w*16 + lr for all
// 4 gates -> acc[4][4], fully lane-local fused LSTM epilogue.
// Phase p (fully unrolled, 16 phases of BK=32):
//   glbA(p+2) [2 dwordx4 fp32, lookahead 2] ->
//   loadB(p)  [4 coalesced dwordx4 from L2-resident Wws -> regs] ->
//   af ds_reads [4 ds_read_b128 from Ab[p&1]] ->
//   writeA(p+1) [auto-wait glbA(p+1); 4 cvt_pk + 1 ds_write_b128 -> other buf]
//     (cvt block + barrier-wait cover the B/L2 and af/LDS latencies) ->
//   16 MFMA (setprio) -> lgkmcnt(0) + s_barrier.
// No manual vmcnt: compiler per-value waits; glbA(p+2) never drained mid-loop.
// A layout: verified conflict-free (64B row stride, granule XOR (row>>1)&3,
// swizzle on per-lane ds_write, matched on ds_read).
__global__ void __launch_bounds__(THREADS, 4)
lstm_main_kernel(const float* __restrict__ x, const float* __restrict__ h_prev,
                 const float* __restrict__ c_prev, const float* __restrict__ bias,
                 const float* __restrict__ pi, const float* __restrict__ pf,
                 const float* __restrict__ po, const short* __restrict__ Wws,
                 float* __restrict__ out) {
    __shared__ short Ab[2][2048];   // 2 x 4 KB bf16 A tiles [64r][32k] swizzled

    const int bid = blockIdx.x;
    const int swz = (bid & 7) * 1024 + (bid >> 3);   // bijective, 8192 % 8 == 0
    const int ut  = swz & 3;
    const int rt  = swz >> 2;
    const int row0 = rt * BM;

    const int t    = threadIdx.x;
    const int lane = t & 63;
    const int w    = t >> 6;             // wave 0..3 = col quarter
    const int lr   = lane & 15;
    const int hi   = lane >> 4;          // k-granule 0..3

    // ---- A staging: thread t -> granule (row t>>2, source slot t&3) ----
    const int ar = t >> 2, as_ = t & 3;
    const int avoff = ((row0 + ar) * 256 + as_ * 8) * 4;          // bytes into x/h
    const int awr   = ar * 32 + ((as_ ^ ((ar >> 1) & 3)) * 8);    // LDS shorts

    // ---- B fragment base: col = g*256 + ut*64 + w*16 + lr, granule hi ----
    const int ucol = ut * 64 + w * 16 + lr;
    const short* wfrag = Wws + ((size_t)ucol << 5) + hi * 8;   // + p*32768 + g*8192

    // ---- A fragment read offset (shorts): swizzle matches write side ----
    const int sw   = (hi ^ ((lr >> 1) & 3)) * 8;
    const int aoff = lr * 32 + sw;       // + m*512

    f32x4 acc[4][4];
    #pragma unroll
    for (int m = 0; m < 4; ++m)
        #pragma unroll
        for (int g = 0; g < 4; ++g)
            acc[m][g] = (f32x4){0.f, 0.f, 0.f, 0.f};

    f32x4 sreg[2][2];                    // two in-flight A register sets (parity)
    auto glbA = [&](int p) {
        const char* base = (const char*)(p < 8 ? x : h_prev) + ((p & 7) << 7);
        sreg[p & 1][0] = *(const f32x4*)(base + avoff);
        sreg[p & 1][1] = *(const f32x4*)(base + avoff + 16);
    };
    auto writeA = [&](int p) {
        const f32x4* s = sreg[p & 1];
        unsigned u0_, u1_, u2_, u3_;
        asm("v_cvt_pk_bf16_f32 %0, %1, %2" : "=v"(u0_) : "v"(s[0][0]), "v"(s[0][1]));
        asm("v_cvt_pk_bf16_f32 %0, %1, %2" : "=v"(u1_) : "v"(s[0][2]), "v"(s[0][3]));
        asm("v_cvt_pk_bf16_f32 %0, %1, %2" : "=v"(u2_) : "v"(s[1][0]), "v"(s[1][1]));
        asm("v_cvt_pk_bf16_f32 %0, %1, %2" : "=v"(u3_) : "v"(s[1][2]), "v"(s[1][3]));
        int4 v = make_int4((int)u0_, (int)u1_, (int)u2_, (int)u3_);
        *(int4*)&Ab[p & 1][awr] = v;
    };

    // ---- prologue: A(0) published; glbA(1) in flight ----
    glbA(0);
    glbA(1);
    writeA(0);                            // auto-wait retires glbA(0) only
    asm volatile("s_waitcnt lgkmcnt(0)" ::: "memory");
    __builtin_amdgcn_s_barrier();

    #pragma unroll
    for (int p = 0; p < 16; ++p) {
        if (p <= 13) glbA(p + 2);         // A lookahead 2

        // B for THIS phase: issue early; covered by cvt block + af reads
        const short* wp = wfrag + ((size_t)p << 15);
        bf16x8 bfr[4];
        #pragma unroll
        for (int g = 0; g < 4; ++g)
            bfr[g] = *(const bf16x8*)(wp + g * 8192);   // coalesced L2 reg load

        // A fragments for THIS phase (buffer p&1, valid since last barrier)
        const short* A = &Ab[p & 1][0];
        bf16x8 af[4];
        #pragma unroll
        for (int m = 0; m < 4; ++m)
            af[m] = *(const bf16x8*)&A[aoff + m * 512];

        if (p <= 14) writeA(p + 1);       // cvt+ds_write to OTHER buffer

        __builtin_amdgcn_s_setprio(1);
        #pragma unroll
        for (int g = 0; g < 4; ++g)
            #pragma unroll
            for (int m = 0; m < 4; ++m)
                acc[m][g] = __builtin_amdgcn_mfma_f32_16x16x32_bf16(af[m], bfr[g], acc[m][g], 0, 0, 0);
        __builtin_amdgcn_s_setprio(0);

        if (p <= 14) {
            asm volatile("s_waitcnt lgkmcnt(0)" ::: "memory");   // A write visible
            __builtin_amdgcn_s_barrier();
        }
    }

    // ---- fused LSTM epilogue (lane-local: all 4 gates in acc[m][0..3]) ----
    const size_t HS = (size_t)NROWS * NUNITS;
    const int u = ucol;
    const float bi = bias[u],       bfg = bias[256 + u];
    const float bc = bias[512 + u], bo  = bias[768 + u];
    const float ppi = pi[u], ppf = pf[u], ppo = po[u];
    #pragma unroll
    for (int m = 0; m < 4; ++m) {
        #pragma unroll
        for (int r = 0; r < 4; ++r) {
            const int row = row0 + m * 16 + hi * 4 + r;
            const size_t o = (size_t)row * NUNITS + u;
            const float cp = c_prev[o];
            float zi = acc[m][0][r] + bi  + ppi * cp;
            float zf = acc[m][1][r] + bfg + ppf * cp;
            float zc = acc[m][2][r] + bc;
            float zo = acc[m][3][r] + bo  + ppo * cp;
            float ig = 1.f / (1.f + __expf(-zi));
            float fg = 1.f / (1.f + __expf(-zf));
            float og = 1.f / (1.f + __expf(-zo));
            zc = fminf(fmaxf(zc, -30.f), 30.f);
            float e2 = __expf(2.f * zc);
            float chat = (e2 - 1.f) / (e2 + 1.f);
            float c  = fg * cp + ig * chat;
            float ccl = fminf(fmaxf(c, -30.f), 30.f);
            float e3 = __expf(2.f * ccl);
            float th = (e3 - 1.f) / (e3 + 1.f);
            float h  = og * th;
            out[o]          = h;
            out[HS + o]     = h;
            out[2 * HS + o] = c;
        }
    }
}

extern "C" void kernel_launch(void* const* d_in, const int* in_sizes, int n_in,
                              void* d_out, int out_size, void* d_ws, size_t ws_size,
                              hipStream_t stream) {
    const float* x  = (const float*)d_in[0];
    const float* h  = (const float*)d_in[1];
    const float* c  = (const float*)d_in[2];
    const float* W  = (const float*)d_in[3];
    const float* b  = (const float*)d_in[4];
    const float* pi = (const float*)d_in[5];
    const float* pf = (const float*)d_in[6];
    const float* po = (const float*)d_in[7];
    float* out = (float*)d_out;

    short* Wws = (short*)d_ws;            // 1 MiB bf16 copy of W in B-frag order

    hipLaunchKernelGGL(convert_W_kernel, dim3(2048), dim3(256), 0, stream, W, Wws);
    hipLaunchKernelGGL(lstm_main_kernel, dim3(NROWS / BM * 4), dim3(THREADS), 0, stream,
                       x, h, c, b, pi, pf, po, Wws, out);
}